// Round 18
// baseline (286.908 us; speedup 1.0000x reference)
//
#include <hip/hip_runtime.h>
#include <hip/hip_fp16.h>

#define NN 100000
#define NE 1600000
#define D 128
#define NG 64
#define BM 64
#define POOL_CHUNK 64
#define SCAN_CHUNK 1024
#define NB_SCAN ((NN + SCAN_CHUNK - 1) / SCAN_CHUNK)   // 98

// CSR-build tiling: 32 edge chunks x 7 node partitions of 16384
// packed counters: low 16 bits = in-degree (dst), high 16 = out-degree (src)
// (NCHUNK 64->32: halves partial-histogram traffic; per-chunk counts ~Poisson(0.5) << 2^16)
#define NCHUNK 32
#define CH_E (NE / NCHUNK)          // 50000 edges per chunk
#define HP 16384                    // nodes per partition (64 KB LDS counters)
#define NPART 7                     // 7*16384 = 114688 >= NN
#define HSTRIDE (NPART * HP)

typedef _Float16 half8 __attribute__((ext_vector_type(8)));
typedef float f32x4 __attribute__((ext_vector_type(4)));

__device__ __forceinline__ int lower_bound_i(const int* a, int n, int key) {
  int lo = 0, hi = n;
  while (lo < hi) { int mid = (lo + hi) >> 1; if (a[mid] < key) lo = mid + 1; else hi = mid; }
  return lo;
}

// partial packed histograms per (chunk, partition): LDS atomics only
__global__ __launch_bounds__(256) void k_hist(
    const int* __restrict__ src, const int* __restrict__ dst,
    int* __restrict__ H) {
  __shared__ int pk[HP];
  const int c = blockIdx.x, p = blockIdx.y, t = threadIdx.x;
  const int base = p * HP;
  for (int i = t; i < HP; i += 256) pk[i] = 0;
  __syncthreads();
  const int4* s4 = (const int4*)(src + c * CH_E);
  const int4* d4 = (const int4*)(dst + c * CH_E);
  const int n4 = CH_E / 4;  // 12500
  for (int i = t; i < n4; i += 256) {
    int4 s = s4[i], d = d4[i];
    if ((unsigned)(d.x - base) < HP) atomicAdd(&pk[d.x - base], 1);
    if ((unsigned)(d.y - base) < HP) atomicAdd(&pk[d.y - base], 1);
    if ((unsigned)(d.z - base) < HP) atomicAdd(&pk[d.z - base], 1);
    if ((unsigned)(d.w - base) < HP) atomicAdd(&pk[d.w - base], 1);
    if ((unsigned)(s.x - base) < HP) atomicAdd(&pk[s.x - base], 65536);
    if ((unsigned)(s.y - base) < HP) atomicAdd(&pk[s.y - base], 65536);
    if ((unsigned)(s.z - base) < HP) atomicAdd(&pk[s.z - base], 65536);
    if ((unsigned)(s.w - base) < HP) atomicAdd(&pk[s.w - base], 65536);
  }
  __syncthreads();
  size_t rb = (size_t)c * HSTRIDE + base;
  for (int i = t; i < HP; i += 256) H[rb + i] = pk[i];
}

// reduce packed partials over chunks -> in-degree (for scan) + both norms
__global__ __launch_bounds__(256) void k_reduce(
    const int* __restrict__ H,
    int* __restrict__ ic, float* __restrict__ onrm, float* __restrict__ inrm) {
  int n = blockIdx.x * 256 + threadIdx.x;
  if (n >= NN) return;
  int si = 0, so = 0;
#pragma unroll 8
  for (int c = 0; c < NCHUNK; ++c) {
    unsigned v = (unsigned)H[(size_t)c * HSTRIDE + n];
    si += (int)(v & 0xffffu);
    so += (int)(v >> 16);
  }
  ic[n] = si;
  inrm[n] = 1.0f / sqrtf((float)max(si, 1));
  onrm[n] = 1.0f / sqrtf((float)max(so, 1));
}

// phase A: per-block chunk sums (coalesced int4, shuffle reduce)
__global__ __launch_bounds__(256) void k_scan_a(const int* __restrict__ cnt,
                                                int* __restrict__ bsum) {
  int b = blockIdx.x, t = threadIdx.x;
  int idx = b * SCAN_CHUNK + t * 4;
  int4 v = make_int4(0, 0, 0, 0);
  if (idx < NN) v = *(const int4*)(cnt + idx);   // NN % 4 == 0
  int s = v.x + v.y + v.z + v.w;
#pragma unroll
  for (int o = 1; o < 64; o <<= 1) s += __shfl_xor(s, o);
  __shared__ int ws[4];
  if ((t & 63) == 0) ws[t >> 6] = s;
  __syncthreads();
  if (t == 0) bsum[b] = ws[0] + ws[1] + ws[2] + ws[3];
}

// phase B: exclusive scan of the 98 block sums (in place), set off[NN]
__global__ void k_scan_b(int* __restrict__ bsum, int* __restrict__ off) {
  __shared__ int s[128];
  int t = threadIdx.x;
  int v = (t < NB_SCAN) ? bsum[t] : 0;
  s[t] = v;
  __syncthreads();
  for (int o = 1; o < 128; o <<= 1) {
    int u = (t >= o) ? s[t - o] : 0;
    __syncthreads();
    s[t] += u;
    __syncthreads();
  }
  if (t < NB_SCAN) bsum[t] = s[t] - v;  // exclusive prefix
  if (t == 0) off[NN] = NE;
}

// phase C: intra-block exclusive scan + block prefix -> off[]
__global__ __launch_bounds__(256) void k_scan_c(const int* __restrict__ cnt,
                                                const int* __restrict__ bsum,
                                                int* __restrict__ off) {
  int b = blockIdx.x, t = threadIdx.x;
  int idx = b * SCAN_CHUNK + t * 4;
  int4 v = make_int4(0, 0, 0, 0);
  if (idx < NN) v = *(const int4*)(cnt + idx);
  int lsum = v.x + v.y + v.z + v.w;
  int lane = t & 63, wid = t >> 6;
  int x = lsum;
#pragma unroll
  for (int o = 1; o < 64; o <<= 1) {
    int u = __shfl_up(x, o);
    if (lane >= o) x += u;
  }
  __shared__ int wsum[4];
  if (lane == 63) wsum[wid] = x;
  __syncthreads();
  int woff = 0;
  for (int i = 0; i < 4; ++i) woff += (i < wid) ? wsum[i] : 0;
  int excl = x - lsum + woff + bsum[b];
  if (idx < NN) {
    int4 o4;
    o4.x = excl;
    o4.y = excl + v.x;
    o4.z = o4.y + v.y;
    o4.w = o4.z + v.z;
    *(int4*)(off + idx) = o4;
  }
}

// column-wise running offsets: H[c][n] <- off[n] + sum_{c'<c} in(H[c'][n])
__global__ __launch_bounds__(256) void k_start(int* __restrict__ H,
                                               const int* __restrict__ off) {
  int n = blockIdx.x * 256 + threadIdx.x;
  if (n >= NN) return;
  int run = off[n];
#pragma unroll 8
  for (int c = 0; c < NCHUNK; ++c) {
    size_t idx = (size_t)c * HSTRIDE + n;
    int v = H[idx];
    H[idx] = run;
    run += (int)((unsigned)v & 0xffffu);
  }
}

// fill CSR: LDS cursors (absolute positions), plain global stores
__global__ __launch_bounds__(256) void k_fill2(
    const int* __restrict__ src, const int* __restrict__ dst,
    const int* __restrict__ H, int* __restrict__ csr) {
  __shared__ int cur[HP];
  const int c = blockIdx.x, p = blockIdx.y, t = threadIdx.x;
  const int base = p * HP;
  size_t rb = (size_t)c * HSTRIDE + base;
  for (int i = t; i < HP; i += 256) cur[i] = H[rb + i];
  __syncthreads();
  const int4* s4 = (const int4*)(src + c * CH_E);
  const int4* d4 = (const int4*)(dst + c * CH_E);
  const int n4 = CH_E / 4;
  for (int i = t; i < n4; i += 256) {
    int4 s = s4[i], d = d4[i];
    if ((unsigned)(d.x - base) < HP) { int pos = atomicAdd(&cur[d.x - base], 1); csr[pos] = s.x; }
    if ((unsigned)(d.y - base) < HP) { int pos = atomicAdd(&cur[d.y - base], 1); csr[pos] = s.y; }
    if ((unsigned)(d.z - base) < HP) { int pos = atomicAdd(&cur[d.z - base], 1); csr[pos] = s.z; }
    if ((unsigned)(d.w - base) < HP) { int pos = atomicAdd(&cur[d.w - base], 1); csr[pos] = s.w; }
  }
}

// MFMA matmul: t[r][c] = fp16( rs[r] * (A[r,:] @ W) ), fp32 accum.
// A is fp32 (layer 1) or fp16 (layer 2), templated. W staged once as fp16
// transposed Wt[c][k] in LDS (pad 136 halves, k8-XOR swizzle -> b128 frag reads).
template <typename AT>
__global__ __launch_bounds__(256, 4) void k_matmul(
    const AT* __restrict__ A, const float* __restrict__ W,
    const float* __restrict__ rs, __half* __restrict__ C) {
  __shared__ _Float16 Wt[128 * 136];
  const int tid = threadIdx.x;
  const int lane = tid & 63, wv = tid >> 6;
  const int row0 = blockIdx.x * BM + wv * 16;
#pragma unroll
  for (int i = 0; i < 16; ++i) {
    int idx = tid + i * 256;              // 0..4095 float4 slots
    int k = idx >> 5, c0 = (idx & 31) * 4;
    float4 w4 = *(const float4*)&W[(size_t)k * 128 + c0];
    int k8 = k >> 3, ko = k & 7;
#pragma unroll
    for (int j = 0; j < 4; ++j) {
      int c = c0 + j;
      int kidx = (((k8 ^ ((c >> 3) & 15)) << 3) | ko);
      float v = (j == 0) ? w4.x : (j == 1) ? w4.y : (j == 2) ? w4.z : w4.w;
      Wt[c * 136 + kidx] = (_Float16)v;
    }
  }
  const int arow = row0 + (lane & 15);
  const bool valid = arow < NN;
  const float sc = valid ? rs[arow] : 0.f;
  half8 afr[4];
#pragma unroll
  for (int s = 0; s < 4; ++s) {
    half8 a;
    if constexpr (sizeof(AT) == 4) {
      const float* ap = (const float*)A + (size_t)arow * D + (lane >> 4) * 8;
      float4 lo = make_float4(0.f, 0.f, 0.f, 0.f), hi = lo;
      if (valid) {
        lo = *(const float4*)(ap + s * 32);
        hi = *(const float4*)(ap + s * 32 + 4);
      }
      a[0] = (_Float16)(lo.x * sc); a[1] = (_Float16)(lo.y * sc);
      a[2] = (_Float16)(lo.z * sc); a[3] = (_Float16)(lo.w * sc);
      a[4] = (_Float16)(hi.x * sc); a[5] = (_Float16)(hi.y * sc);
      a[6] = (_Float16)(hi.z * sc); a[7] = (_Float16)(hi.w * sc);
    } else {
      const _Float16* ap = (const _Float16*)A + (size_t)arow * D + (lane >> 4) * 8;
      half8 raw = {};
      if (valid) raw = *(const half8*)(ap + s * 32);
#pragma unroll
      for (int j = 0; j < 8; ++j) a[j] = (_Float16)((float)raw[j] * sc);
    }
    afr[s] = a;
  }
  __syncthreads();
  f32x4 acc[8];
#pragma unroll
  for (int ct = 0; ct < 8; ++ct) acc[ct] = (f32x4){0.f, 0.f, 0.f, 0.f};
#pragma unroll
  for (int s = 0; s < 4; ++s) {
    const int k8 = s * 4 + (lane >> 4);
#pragma unroll
    for (int ct = 0; ct < 8; ++ct) {
      int c = ct * 16 + (lane & 15);
      int kidx = ((k8 ^ ((c >> 3) & 15)) << 3);
      half8 b = *(const half8*)&Wt[c * 136 + kidx];
      acc[ct] = __builtin_amdgcn_mfma_f32_16x16x32_f16(afr[s], b, acc[ct], 0, 0, 0);
    }
  }
  const int dcol = lane & 15;
  const int drow0 = row0 + (lane >> 4) * 4;
#pragma unroll
  for (int ct = 0; ct < 8; ++ct) {
#pragma unroll
    for (int r = 0; r < 4; ++r) {
      int row = drow0 + r;
      if (row < NN)
        C[(size_t)row * D + ct * 16 + dcol] = __float2half_rn(acc[ct][r]);
    }
  }
}

// out[d,:] = fp16(relu(in_norm[d] * sum_{s in CSR(d)} t[s,:] + bias))
// one wave per dst node; 4 lane-groups of 16, 16B per lane per edge.
// Unrolled x4: four independent index+row loads in flight per subgroup.
__global__ __launch_bounds__(256) void k_gather(
    const __half* __restrict__ t, const int* __restrict__ csr,
    const int* __restrict__ off, const float* __restrict__ inn,
    const float* __restrict__ bias, __half* __restrict__ outp) {
  int w = (blockIdx.x * blockDim.x + threadIdx.x) >> 6;
  int lane = threadIdx.x & 63;
  if (w >= NN) return;
  int lo = off[w], hi = off[w + 1];
  const int g = lane >> 4;        // edge subgroup 0..3
  const int li = lane & 15;       // 16B column slot
  const __half* tp = t + li * 8;
  float a0 = 0.f, a1 = 0.f, a2 = 0.f, a3 = 0.f;
  float a4 = 0.f, a5 = 0.f, a6 = 0.f, a7 = 0.f;
  int e = lo + g;
  for (; e + 12 < hi; e += 16) {
    int s0 = csr[e];
    int s1 = csr[e + 4];
    int s2 = csr[e + 8];
    int s3 = csr[e + 12];
    float4 r0 = *(const float4*)(tp + (size_t)s0 * D);
    float4 r1 = *(const float4*)(tp + (size_t)s1 * D);
    float4 r2 = *(const float4*)(tp + (size_t)s2 * D);
    float4 r3 = *(const float4*)(tp + (size_t)s3 * D);
    const __half2* h0 = (const __half2*)&r0;
    const __half2* h1 = (const __half2*)&r1;
    const __half2* h2 = (const __half2*)&r2;
    const __half2* h3 = (const __half2*)&r3;
    float2 f00 = __half22float2(h0[0]), f01 = __half22float2(h0[1]);
    float2 f02 = __half22float2(h0[2]), f03 = __half22float2(h0[3]);
    float2 f10 = __half22float2(h1[0]), f11 = __half22float2(h1[1]);
    float2 f12 = __half22float2(h1[2]), f13 = __half22float2(h1[3]);
    float2 f20 = __half22float2(h2[0]), f21 = __half22float2(h2[1]);
    float2 f22 = __half22float2(h2[2]), f23 = __half22float2(h2[3]);
    float2 f30 = __half22float2(h3[0]), f31 = __half22float2(h3[1]);
    float2 f32 = __half22float2(h3[2]), f33 = __half22float2(h3[3]);
    a0 += (f00.x + f10.x) + (f20.x + f30.x);
    a1 += (f00.y + f10.y) + (f20.y + f30.y);
    a2 += (f01.x + f11.x) + (f21.x + f31.x);
    a3 += (f01.y + f11.y) + (f21.y + f31.y);
    a4 += (f02.x + f12.x) + (f22.x + f32.x);
    a5 += (f02.y + f12.y) + (f22.y + f32.y);
    a6 += (f03.x + f13.x) + (f23.x + f33.x);
    a7 += (f03.y + f13.y) + (f23.y + f33.y);
  }
  for (; e < hi; e += 4) {
    int s0 = csr[e];
    float4 r0 = *(const float4*)(tp + (size_t)s0 * D);
    const __half2* h0 = (const __half2*)&r0;
    float2 f00 = __half22float2(h0[0]), f01 = __half22float2(h0[1]);
    float2 f02 = __half22float2(h0[2]), f03 = __half22float2(h0[3]);
    a0 += f00.x; a1 += f00.y; a2 += f01.x; a3 += f01.y;
    a4 += f02.x; a5 += f02.y; a6 += f03.x; a7 += f03.y;
  }
  a0 += __shfl_xor(a0, 16); a0 += __shfl_xor(a0, 32);
  a1 += __shfl_xor(a1, 16); a1 += __shfl_xor(a1, 32);
  a2 += __shfl_xor(a2, 16); a2 += __shfl_xor(a2, 32);
  a3 += __shfl_xor(a3, 16); a3 += __shfl_xor(a3, 32);
  a4 += __shfl_xor(a4, 16); a4 += __shfl_xor(a4, 32);
  a5 += __shfl_xor(a5, 16); a5 += __shfl_xor(a5, 32);
  a6 += __shfl_xor(a6, 16); a6 += __shfl_xor(a6, 32);
  a7 += __shfl_xor(a7, 16); a7 += __shfl_xor(a7, 32);
  if (lane < 16) {
    float nm = inn[w];
    float4 b0 = *(const float4*)(bias + li * 8);
    float4 b1 = *(const float4*)(bias + li * 8 + 4);
    float o0 = fmaxf(fmaf(nm, a0, b0.x), 0.f);
    float o1 = fmaxf(fmaf(nm, a1, b0.y), 0.f);
    float o2 = fmaxf(fmaf(nm, a2, b0.z), 0.f);
    float o3 = fmaxf(fmaf(nm, a3, b0.w), 0.f);
    float o4 = fmaxf(fmaf(nm, a4, b1.x), 0.f);
    float o5 = fmaxf(fmaf(nm, a5, b1.y), 0.f);
    float o6 = fmaxf(fmaf(nm, a6, b1.z), 0.f);
    float o7 = fmaxf(fmaf(nm, a7, b1.w), 0.f);
    uint4 u;
    u.x = (unsigned)__half_as_ushort(__float2half_rn(o0)) |
          ((unsigned)__half_as_ushort(__float2half_rn(o1)) << 16);
    u.y = (unsigned)__half_as_ushort(__float2half_rn(o2)) |
          ((unsigned)__half_as_ushort(__float2half_rn(o3)) << 16);
    u.z = (unsigned)__half_as_ushort(__float2half_rn(o4)) |
          ((unsigned)__half_as_ushort(__float2half_rn(o5)) << 16);
    u.w = (unsigned)__half_as_ushort(__float2half_rn(o6)) |
          ((unsigned)__half_as_ushort(__float2half_rn(o7)) << 16);
    *(uint4*)(outp + (size_t)w * D + li * 8) = u;
  }
}

// parallel pool partial sums over fp16 h2: block = 64-node chunk, thread = col
__global__ __launch_bounds__(128) void k_pool_partial(
    const __half* __restrict__ h2, const int* __restrict__ n2g,
    float* __restrict__ sums) {
  int c = threadIdx.x;
  int n0 = blockIdx.x * POOL_CHUNK;
  int n1 = min(n0 + POOL_CHUNK, NN);
  if (n0 >= NN) return;
  int gcur = n2g[n0];
  float acc = 0.f;
  for (int n = n0; n < n1; ++n) {
    int g = n2g[n];
    if (g != gcur) {
      atomicAdd(&sums[gcur * D + c], acc);
      acc = 0.f;
      gcur = g;
    }
    acc += __half2float(h2[(size_t)n * D + c]);
  }
  atomicAdd(&sums[gcur * D + c], acc);
}

// 3-layer MLP head; one block per graph, 128 threads. Divides sums by count.
__global__ void k_mlp(const float* __restrict__ sums, const int* __restrict__ n2g,
                      const float* __restrict__ Wc1, const float* __restrict__ bc1,
                      const float* __restrict__ Wc2, const float* __restrict__ bc2,
                      const float* __restrict__ Wc3, const float* __restrict__ bc3,
                      float* __restrict__ out) {
  __shared__ float xin[128];
  __shared__ float x1[128];
  __shared__ float red[128];
  int g = blockIdx.x, j = threadIdx.x;
  int start = lower_bound_i(n2g, NN, g);
  int end = lower_bound_i(n2g, NN, g + 1);
  float inv = 1.0f / (float)max(end - start, 1);
  xin[j] = sums[g * D + j] * inv;
  __syncthreads();
  float s = bc1[j];
#pragma unroll 8
  for (int k = 0; k < 128; ++k) s = fmaf(xin[k], Wc1[k * D + j], s);
  x1[j] = fmaxf(s, 0.f);
  __syncthreads();
  float s2 = bc2[j];
#pragma unroll 8
  for (int k = 0; k < 128; ++k) s2 = fmaf(x1[k], Wc2[k * D + j], s2);
  float v2 = fmaxf(s2, 0.f);
  red[j] = v2 * Wc3[j];
  __syncthreads();
  for (int o = 64; o > 0; o >>= 1) {
    if (j < o) red[j] += red[j + o];
    __syncthreads();
  }
  if (j == 0) out[g] = red[0] + bc3[0];
}

extern "C" void kernel_launch(void* const* d_in, const int* in_sizes, int n_in,
                              void* d_out, int out_size, void* d_ws, size_t ws_size,
                              hipStream_t stream) {
  const float* h   = (const float*)d_in[0];
  const int* src   = (const int*)d_in[1];
  const int* dst   = (const int*)d_in[2];
  const int* n2g   = (const int*)d_in[3];
  const float* W1  = (const float*)d_in[4];
  const float* b1  = (const float*)d_in[5];
  const float* W2  = (const float*)d_in[6];
  const float* b2  = (const float*)d_in[7];
  const float* Wc1 = (const float*)d_in[8];
  const float* bc1 = (const float*)d_in[9];
  const float* Wc2 = (const float*)d_in[10];
  const float* bc2 = (const float*)d_in[11];
  const float* Wc3 = (const float*)d_in[12];
  const float* bc3 = (const float*)d_in[13];
  float* out = (float*)d_out;

  char* p = (char*)d_ws;
  size_t o = 0;
  auto take = [&](size_t b) { void* q = p + o; o = (o + b + 255) & ~(size_t)255; return q; };
  float* sums = (float*)take(NG * D * 4);
  size_t zero_bytes = o;                    // zero pool sums only
  int* off   = (int*)take((NN + 1) * 4);
  int* bsum  = (int*)take(NB_SCAN * 4);
  int* ic    = (int*)take(NN * 4);
  float* onrm = (float*)take(NN * 4);
  float* inrm = (float*)take(NN * 4);
  int* csr   = (int*)take((size_t)NE * 4);
  __half* tbuf = (__half*)take((size_t)NN * D * 2);   // t (25.6 MB, fp16)
  __half* hbuf = (__half*)take((size_t)NN * D * 4);   // h1/h2 fp16 in 51.2 MB slot
  (void)ws_size; (void)in_sizes; (void)n_in; (void)out_size;

  // packed partial histograms alias the hbuf slot (14.7 MB <= 51.2 MB);
  // CSR build completes before gather1 first writes hbuf
  int* H = (int*)hbuf;

  hipMemsetAsync(d_ws, 0, zero_bytes, stream);
  dim3 hgrid(NCHUNK, NPART);
  k_hist<<<hgrid, 256, 0, stream>>>(src, dst, H);
  k_reduce<<<(NN + 255) / 256, 256, 0, stream>>>(H, ic, onrm, inrm);
  k_scan_a<<<NB_SCAN, 256, 0, stream>>>(ic, bsum);
  k_scan_b<<<1, 128, 0, stream>>>(bsum, off);
  k_scan_c<<<NB_SCAN, 256, 0, stream>>>(ic, bsum, off);
  k_start<<<(NN + 255) / 256, 256, 0, stream>>>(H, off);
  k_fill2<<<hgrid, 256, 0, stream>>>(src, dst, H, csr);

  // layer 1: t = fp16((h * onrm) @ W1); h1 = fp16(relu(inrm * gather(t) + b1))
  k_matmul<float><<<(NN + BM - 1) / BM, 256, 0, stream>>>(h, W1, onrm, tbuf);
  k_gather<<<(NN * 64) / 256, 256, 0, stream>>>(tbuf, csr, off, inrm, b1, hbuf);
  // layer 2
  k_matmul<__half><<<(NN + BM - 1) / BM, 256, 0, stream>>>(hbuf, W2, onrm, tbuf);
  k_gather<<<(NN * 64) / 256, 256, 0, stream>>>(tbuf, csr, off, inrm, b2, hbuf);

  k_pool_partial<<<(NN + POOL_CHUNK - 1) / POOL_CHUNK, 128, 0, stream>>>(hbuf, n2g, sums);
  k_mlp<<<NG, 128, 0, stream>>>(sums, n2g, Wc1, bc1, Wc2, bc2, Wc3, bc3, out);
}

// Round 19
// 271.607 us; speedup vs baseline: 1.0563x; 1.0563x over previous
//
#include <hip/hip_runtime.h>
#include <hip/hip_fp16.h>

#define NN 100000
#define NE 1600000
#define D 128
#define NG 64
#define BM 64
#define POOL_CHUNK 64
#define SCAN_CHUNK 1024
#define NB_SCAN ((NN + SCAN_CHUNK - 1) / SCAN_CHUNK)   // 98

// CSR-build tiling: 64 edge chunks x 7 node partitions of 16384
// packed counters: low 16 bits = in-degree (dst), high 16 = out-degree (src)
// (NCHUNK=64 verified optimal: 32 regressed -14us [R18: occupancy], byte-pack broke [R8])
#define NCHUNK 64
#define CH_E (NE / NCHUNK)          // 25000 edges per chunk
#define HP 16384                    // nodes per partition (64 KB LDS counters)
#define NPART 7                     // 7*16384 = 114688 >= NN
#define HSTRIDE (NPART * HP)

typedef _Float16 half8 __attribute__((ext_vector_type(8)));
typedef float f32x4 __attribute__((ext_vector_type(4)));

__device__ __forceinline__ int lower_bound_i(const int* a, int n, int key) {
  int lo = 0, hi = n;
  while (lo < hi) { int mid = (lo + hi) >> 1; if (a[mid] < key) lo = mid + 1; else hi = mid; }
  return lo;
}

// partial packed histograms per (chunk, partition): LDS atomics only
__global__ __launch_bounds__(256) void k_hist(
    const int* __restrict__ src, const int* __restrict__ dst,
    int* __restrict__ H) {
  __shared__ int pk[HP];
  const int c = blockIdx.x, p = blockIdx.y, t = threadIdx.x;
  const int base = p * HP;
  for (int i = t; i < HP; i += 256) pk[i] = 0;
  __syncthreads();
  const int4* s4 = (const int4*)(src + c * CH_E);
  const int4* d4 = (const int4*)(dst + c * CH_E);
  const int n4 = CH_E / 4;  // 6250
  for (int i = t; i < n4; i += 256) {
    int4 s = s4[i], d = d4[i];
    if ((unsigned)(d.x - base) < HP) atomicAdd(&pk[d.x - base], 1);
    if ((unsigned)(d.y - base) < HP) atomicAdd(&pk[d.y - base], 1);
    if ((unsigned)(d.z - base) < HP) atomicAdd(&pk[d.z - base], 1);
    if ((unsigned)(d.w - base) < HP) atomicAdd(&pk[d.w - base], 1);
    if ((unsigned)(s.x - base) < HP) atomicAdd(&pk[s.x - base], 65536);
    if ((unsigned)(s.y - base) < HP) atomicAdd(&pk[s.y - base], 65536);
    if ((unsigned)(s.z - base) < HP) atomicAdd(&pk[s.z - base], 65536);
    if ((unsigned)(s.w - base) < HP) atomicAdd(&pk[s.w - base], 65536);
  }
  __syncthreads();
  size_t rb = (size_t)c * HSTRIDE + base;
  for (int i = t; i < HP; i += 256) H[rb + i] = pk[i];
}

// reduce packed partials over chunks -> in-degree (for scan) + both norms
__global__ __launch_bounds__(256) void k_reduce(
    const int* __restrict__ H,
    int* __restrict__ ic, float* __restrict__ onrm, float* __restrict__ inrm) {
  int n = blockIdx.x * 256 + threadIdx.x;
  if (n >= NN) return;
  int si = 0, so = 0;
#pragma unroll 8
  for (int c = 0; c < NCHUNK; ++c) {
    unsigned v = (unsigned)H[(size_t)c * HSTRIDE + n];
    si += (int)(v & 0xffffu);
    so += (int)(v >> 16);
  }
  ic[n] = si;
  inrm[n] = 1.0f / sqrtf((float)max(si, 1));
  onrm[n] = 1.0f / sqrtf((float)max(so, 1));
}

// phase A: per-block chunk sums (coalesced int4, shuffle reduce)
__global__ __launch_bounds__(256) void k_scan_a(const int* __restrict__ cnt,
                                                int* __restrict__ bsum) {
  int b = blockIdx.x, t = threadIdx.x;
  int idx = b * SCAN_CHUNK + t * 4;
  int4 v = make_int4(0, 0, 0, 0);
  if (idx < NN) v = *(const int4*)(cnt + idx);   // NN % 4 == 0
  int s = v.x + v.y + v.z + v.w;
#pragma unroll
  for (int o = 1; o < 64; o <<= 1) s += __shfl_xor(s, o);
  __shared__ int ws[4];
  if ((t & 63) == 0) ws[t >> 6] = s;
  __syncthreads();
  if (t == 0) bsum[b] = ws[0] + ws[1] + ws[2] + ws[3];
}

// phase B: exclusive scan of the 98 block sums (in place), set off[NN]
__global__ void k_scan_b(int* __restrict__ bsum, int* __restrict__ off) {
  __shared__ int s[128];
  int t = threadIdx.x;
  int v = (t < NB_SCAN) ? bsum[t] : 0;
  s[t] = v;
  __syncthreads();
  for (int o = 1; o < 128; o <<= 1) {
    int u = (t >= o) ? s[t - o] : 0;
    __syncthreads();
    s[t] += u;
    __syncthreads();
  }
  if (t < NB_SCAN) bsum[t] = s[t] - v;  // exclusive prefix
  if (t == 0) off[NN] = NE;
}

// phase C: intra-block exclusive scan + block prefix -> off[]
__global__ __launch_bounds__(256) void k_scan_c(const int* __restrict__ cnt,
                                                const int* __restrict__ bsum,
                                                int* __restrict__ off) {
  int b = blockIdx.x, t = threadIdx.x;
  int idx = b * SCAN_CHUNK + t * 4;
  int4 v = make_int4(0, 0, 0, 0);
  if (idx < NN) v = *(const int4*)(cnt + idx);
  int lsum = v.x + v.y + v.z + v.w;
  int lane = t & 63, wid = t >> 6;
  int x = lsum;
#pragma unroll
  for (int o = 1; o < 64; o <<= 1) {
    int u = __shfl_up(x, o);
    if (lane >= o) x += u;
  }
  __shared__ int wsum[4];
  if (lane == 63) wsum[wid] = x;
  __syncthreads();
  int woff = 0;
  for (int i = 0; i < 4; ++i) woff += (i < wid) ? wsum[i] : 0;
  int excl = x - lsum + woff + bsum[b];
  if (idx < NN) {
    int4 o4;
    o4.x = excl;
    o4.y = excl + v.x;
    o4.z = o4.y + v.y;
    o4.w = o4.z + v.z;
    *(int4*)(off + idx) = o4;
  }
}

// column-wise running offsets: H[c][n] <- off[n] + sum_{c'<c} in(H[c'][n])
__global__ __launch_bounds__(256) void k_start(int* __restrict__ H,
                                               const int* __restrict__ off) {
  int n = blockIdx.x * 256 + threadIdx.x;
  if (n >= NN) return;
  int run = off[n];
#pragma unroll 8
  for (int c = 0; c < NCHUNK; ++c) {
    size_t idx = (size_t)c * HSTRIDE + n;
    int v = H[idx];
    H[idx] = run;
    run += (int)((unsigned)v & 0xffffu);
  }
}

// fill CSR: LDS cursors (absolute positions), plain global stores
__global__ __launch_bounds__(256) void k_fill2(
    const int* __restrict__ src, const int* __restrict__ dst,
    const int* __restrict__ H, int* __restrict__ csr) {
  __shared__ int cur[HP];
  const int c = blockIdx.x, p = blockIdx.y, t = threadIdx.x;
  const int base = p * HP;
  size_t rb = (size_t)c * HSTRIDE + base;
  for (int i = t; i < HP; i += 256) cur[i] = H[rb + i];
  __syncthreads();
  const int4* s4 = (const int4*)(src + c * CH_E);
  const int4* d4 = (const int4*)(dst + c * CH_E);
  const int n4 = CH_E / 4;
  for (int i = t; i < n4; i += 256) {
    int4 s = s4[i], d = d4[i];
    if ((unsigned)(d.x - base) < HP) { int pos = atomicAdd(&cur[d.x - base], 1); csr[pos] = s.x; }
    if ((unsigned)(d.y - base) < HP) { int pos = atomicAdd(&cur[d.y - base], 1); csr[pos] = s.y; }
    if ((unsigned)(d.z - base) < HP) { int pos = atomicAdd(&cur[d.z - base], 1); csr[pos] = s.z; }
    if ((unsigned)(d.w - base) < HP) { int pos = atomicAdd(&cur[d.w - base], 1); csr[pos] = s.w; }
  }
}

// MFMA matmul: t[r][c] = fp16( rs[r] * (A[r,:] @ W) ), fp32 accum.
// A is fp32 (layer 1) or fp16 (layer 2), templated. W staged once as fp16
// transposed Wt[c][k] in LDS (pad 136 halves, k8-XOR swizzle -> b128 frag reads).
template <typename AT>
__global__ __launch_bounds__(256, 4) void k_matmul(
    const AT* __restrict__ A, const float* __restrict__ W,
    const float* __restrict__ rs, __half* __restrict__ C) {
  __shared__ _Float16 Wt[128 * 136];
  const int tid = threadIdx.x;
  const int lane = tid & 63, wv = tid >> 6;
  const int row0 = blockIdx.x * BM + wv * 16;
#pragma unroll
  for (int i = 0; i < 16; ++i) {
    int idx = tid + i * 256;              // 0..4095 float4 slots
    int k = idx >> 5, c0 = (idx & 31) * 4;
    float4 w4 = *(const float4*)&W[(size_t)k * 128 + c0];
    int k8 = k >> 3, ko = k & 7;
#pragma unroll
    for (int j = 0; j < 4; ++j) {
      int c = c0 + j;
      int kidx = (((k8 ^ ((c >> 3) & 15)) << 3) | ko);
      float v = (j == 0) ? w4.x : (j == 1) ? w4.y : (j == 2) ? w4.z : w4.w;
      Wt[c * 136 + kidx] = (_Float16)v;
    }
  }
  const int arow = row0 + (lane & 15);
  const bool valid = arow < NN;
  const float sc = valid ? rs[arow] : 0.f;
  half8 afr[4];
#pragma unroll
  for (int s = 0; s < 4; ++s) {
    half8 a;
    if constexpr (sizeof(AT) == 4) {
      const float* ap = (const float*)A + (size_t)arow * D + (lane >> 4) * 8;
      float4 lo = make_float4(0.f, 0.f, 0.f, 0.f), hi = lo;
      if (valid) {
        lo = *(const float4*)(ap + s * 32);
        hi = *(const float4*)(ap + s * 32 + 4);
      }
      a[0] = (_Float16)(lo.x * sc); a[1] = (_Float16)(lo.y * sc);
      a[2] = (_Float16)(lo.z * sc); a[3] = (_Float16)(lo.w * sc);
      a[4] = (_Float16)(hi.x * sc); a[5] = (_Float16)(hi.y * sc);
      a[6] = (_Float16)(hi.z * sc); a[7] = (_Float16)(hi.w * sc);
    } else {
      const _Float16* ap = (const _Float16*)A + (size_t)arow * D + (lane >> 4) * 8;
      half8 raw = {};
      if (valid) raw = *(const half8*)(ap + s * 32);
#pragma unroll
      for (int j = 0; j < 8; ++j) a[j] = (_Float16)((float)raw[j] * sc);
    }
    afr[s] = a;
  }
  __syncthreads();
  f32x4 acc[8];
#pragma unroll
  for (int ct = 0; ct < 8; ++ct) acc[ct] = (f32x4){0.f, 0.f, 0.f, 0.f};
#pragma unroll
  for (int s = 0; s < 4; ++s) {
    const int k8 = s * 4 + (lane >> 4);
#pragma unroll
    for (int ct = 0; ct < 8; ++ct) {
      int c = ct * 16 + (lane & 15);
      int kidx = ((k8 ^ ((c >> 3) & 15)) << 3);
      half8 b = *(const half8*)&Wt[c * 136 + kidx];
      acc[ct] = __builtin_amdgcn_mfma_f32_16x16x32_f16(afr[s], b, acc[ct], 0, 0, 0);
    }
  }
  const int dcol = lane & 15;
  const int drow0 = row0 + (lane >> 4) * 4;
#pragma unroll
  for (int ct = 0; ct < 8; ++ct) {
#pragma unroll
    for (int r = 0; r < 4; ++r) {
      int row = drow0 + r;
      if (row < NN)
        C[(size_t)row * D + ct * 16 + dcol] = __float2half_rn(acc[ct][r]);
    }
  }
}

// out[d,:] = fp16(relu(in_norm[d] * sum_{s in CSR(d)} t[s,:] + bias))
// one wave per dst node; 4 lane-groups of 16, 16B per lane per edge.
// Unrolled x4: four independent index+row loads in flight per subgroup.
__global__ __launch_bounds__(256) void k_gather(
    const __half* __restrict__ t, const int* __restrict__ csr,
    const int* __restrict__ off, const float* __restrict__ inn,
    const float* __restrict__ bias, __half* __restrict__ outp) {
  int w = (blockIdx.x * blockDim.x + threadIdx.x) >> 6;
  int lane = threadIdx.x & 63;
  if (w >= NN) return;
  int lo = off[w], hi = off[w + 1];
  const int g = lane >> 4;        // edge subgroup 0..3
  const int li = lane & 15;       // 16B column slot
  const __half* tp = t + li * 8;
  float a0 = 0.f, a1 = 0.f, a2 = 0.f, a3 = 0.f;
  float a4 = 0.f, a5 = 0.f, a6 = 0.f, a7 = 0.f;
  int e = lo + g;
  for (; e + 12 < hi; e += 16) {
    int s0 = csr[e];
    int s1 = csr[e + 4];
    int s2 = csr[e + 8];
    int s3 = csr[e + 12];
    float4 r0 = *(const float4*)(tp + (size_t)s0 * D);
    float4 r1 = *(const float4*)(tp + (size_t)s1 * D);
    float4 r2 = *(const float4*)(tp + (size_t)s2 * D);
    float4 r3 = *(const float4*)(tp + (size_t)s3 * D);
    const __half2* h0 = (const __half2*)&r0;
    const __half2* h1 = (const __half2*)&r1;
    const __half2* h2 = (const __half2*)&r2;
    const __half2* h3 = (const __half2*)&r3;
    float2 f00 = __half22float2(h0[0]), f01 = __half22float2(h0[1]);
    float2 f02 = __half22float2(h0[2]), f03 = __half22float2(h0[3]);
    float2 f10 = __half22float2(h1[0]), f11 = __half22float2(h1[1]);
    float2 f12 = __half22float2(h1[2]), f13 = __half22float2(h1[3]);
    float2 f20 = __half22float2(h2[0]), f21 = __half22float2(h2[1]);
    float2 f22 = __half22float2(h2[2]), f23 = __half22float2(h2[3]);
    float2 f30 = __half22float2(h3[0]), f31 = __half22float2(h3[1]);
    float2 f32 = __half22float2(h3[2]), f33 = __half22float2(h3[3]);
    a0 += (f00.x + f10.x) + (f20.x + f30.x);
    a1 += (f00.y + f10.y) + (f20.y + f30.y);
    a2 += (f01.x + f11.x) + (f21.x + f31.x);
    a3 += (f01.y + f11.y) + (f21.y + f31.y);
    a4 += (f02.x + f12.x) + (f22.x + f32.x);
    a5 += (f02.y + f12.y) + (f22.y + f32.y);
    a6 += (f03.x + f13.x) + (f23.x + f33.x);
    a7 += (f03.y + f13.y) + (f23.y + f33.y);
  }
  for (; e < hi; e += 4) {
    int s0 = csr[e];
    float4 r0 = *(const float4*)(tp + (size_t)s0 * D);
    const __half2* h0 = (const __half2*)&r0;
    float2 f00 = __half22float2(h0[0]), f01 = __half22float2(h0[1]);
    float2 f02 = __half22float2(h0[2]), f03 = __half22float2(h0[3]);
    a0 += f00.x; a1 += f00.y; a2 += f01.x; a3 += f01.y;
    a4 += f02.x; a5 += f02.y; a6 += f03.x; a7 += f03.y;
  }
  a0 += __shfl_xor(a0, 16); a0 += __shfl_xor(a0, 32);
  a1 += __shfl_xor(a1, 16); a1 += __shfl_xor(a1, 32);
  a2 += __shfl_xor(a2, 16); a2 += __shfl_xor(a2, 32);
  a3 += __shfl_xor(a3, 16); a3 += __shfl_xor(a3, 32);
  a4 += __shfl_xor(a4, 16); a4 += __shfl_xor(a4, 32);
  a5 += __shfl_xor(a5, 16); a5 += __shfl_xor(a5, 32);
  a6 += __shfl_xor(a6, 16); a6 += __shfl_xor(a6, 32);
  a7 += __shfl_xor(a7, 16); a7 += __shfl_xor(a7, 32);
  if (lane < 16) {
    float nm = inn[w];
    float4 b0 = *(const float4*)(bias + li * 8);
    float4 b1 = *(const float4*)(bias + li * 8 + 4);
    float o0 = fmaxf(fmaf(nm, a0, b0.x), 0.f);
    float o1 = fmaxf(fmaf(nm, a1, b0.y), 0.f);
    float o2 = fmaxf(fmaf(nm, a2, b0.z), 0.f);
    float o3 = fmaxf(fmaf(nm, a3, b0.w), 0.f);
    float o4 = fmaxf(fmaf(nm, a4, b1.x), 0.f);
    float o5 = fmaxf(fmaf(nm, a5, b1.y), 0.f);
    float o6 = fmaxf(fmaf(nm, a6, b1.z), 0.f);
    float o7 = fmaxf(fmaf(nm, a7, b1.w), 0.f);
    uint4 u;
    u.x = (unsigned)__half_as_ushort(__float2half_rn(o0)) |
          ((unsigned)__half_as_ushort(__float2half_rn(o1)) << 16);
    u.y = (unsigned)__half_as_ushort(__float2half_rn(o2)) |
          ((unsigned)__half_as_ushort(__float2half_rn(o3)) << 16);
    u.z = (unsigned)__half_as_ushort(__float2half_rn(o4)) |
          ((unsigned)__half_as_ushort(__float2half_rn(o5)) << 16);
    u.w = (unsigned)__half_as_ushort(__float2half_rn(o6)) |
          ((unsigned)__half_as_ushort(__float2half_rn(o7)) << 16);
    *(uint4*)(outp + (size_t)w * D + li * 8) = u;
  }
}

// parallel pool partial sums over fp16 h2: block = 64-node chunk, thread = col
__global__ __launch_bounds__(128) void k_pool_partial(
    const __half* __restrict__ h2, const int* __restrict__ n2g,
    float* __restrict__ sums) {
  int c = threadIdx.x;
  int n0 = blockIdx.x * POOL_CHUNK;
  int n1 = min(n0 + POOL_CHUNK, NN);
  if (n0 >= NN) return;
  int gcur = n2g[n0];
  float acc = 0.f;
  for (int n = n0; n < n1; ++n) {
    int g = n2g[n];
    if (g != gcur) {
      atomicAdd(&sums[gcur * D + c], acc);
      acc = 0.f;
      gcur = g;
    }
    acc += __half2float(h2[(size_t)n * D + c]);
  }
  atomicAdd(&sums[gcur * D + c], acc);
}

// 3-layer MLP head; one block per graph, 128 threads. Divides sums by count.
__global__ void k_mlp(const float* __restrict__ sums, const int* __restrict__ n2g,
                      const float* __restrict__ Wc1, const float* __restrict__ bc1,
                      const float* __restrict__ Wc2, const float* __restrict__ bc2,
                      const float* __restrict__ Wc3, const float* __restrict__ bc3,
                      float* __restrict__ out) {
  __shared__ float xin[128];
  __shared__ float x1[128];
  __shared__ float red[128];
  int g = blockIdx.x, j = threadIdx.x;
  int start = lower_bound_i(n2g, NN, g);
  int end = lower_bound_i(n2g, NN, g + 1);
  float inv = 1.0f / (float)max(end - start, 1);
  xin[j] = sums[g * D + j] * inv;
  __syncthreads();
  float s = bc1[j];
#pragma unroll 8
  for (int k = 0; k < 128; ++k) s = fmaf(xin[k], Wc1[k * D + j], s);
  x1[j] = fmaxf(s, 0.f);
  __syncthreads();
  float s2 = bc2[j];
#pragma unroll 8
  for (int k = 0; k < 128; ++k) s2 = fmaf(x1[k], Wc2[k * D + j], s2);
  float v2 = fmaxf(s2, 0.f);
  red[j] = v2 * Wc3[j];
  __syncthreads();
  for (int o = 64; o > 0; o >>= 1) {
    if (j < o) red[j] += red[j + o];
    __syncthreads();
  }
  if (j == 0) out[g] = red[0] + bc3[0];
}

extern "C" void kernel_launch(void* const* d_in, const int* in_sizes, int n_in,
                              void* d_out, int out_size, void* d_ws, size_t ws_size,
                              hipStream_t stream) {
  const float* h   = (const float*)d_in[0];
  const int* src   = (const int*)d_in[1];
  const int* dst   = (const int*)d_in[2];
  const int* n2g   = (const int*)d_in[3];
  const float* W1  = (const float*)d_in[4];
  const float* b1  = (const float*)d_in[5];
  const float* W2  = (const float*)d_in[6];
  const float* b2  = (const float*)d_in[7];
  const float* Wc1 = (const float*)d_in[8];
  const float* bc1 = (const float*)d_in[9];
  const float* Wc2 = (const float*)d_in[10];
  const float* bc2 = (const float*)d_in[11];
  const float* Wc3 = (const float*)d_in[12];
  const float* bc3 = (const float*)d_in[13];
  float* out = (float*)d_out;

  char* p = (char*)d_ws;
  size_t o = 0;
  auto take = [&](size_t b) { void* q = p + o; o = (o + b + 255) & ~(size_t)255; return q; };
  float* sums = (float*)take(NG * D * 4);
  size_t zero_bytes = o;                    // zero pool sums only
  int* off   = (int*)take((NN + 1) * 4);
  int* bsum  = (int*)take(NB_SCAN * 4);
  int* ic    = (int*)take(NN * 4);
  float* onrm = (float*)take(NN * 4);
  float* inrm = (float*)take(NN * 4);
  int* csr   = (int*)take((size_t)NE * 4);
  __half* tbuf = (__half*)take((size_t)NN * D * 2);   // t (25.6 MB, fp16)
  __half* hbuf = (__half*)take((size_t)NN * D * 4);   // h1/h2 fp16 in 51.2 MB slot
  (void)ws_size; (void)in_sizes; (void)n_in; (void)out_size;

  // packed partial histograms alias the hbuf slot (29.4 MB <= 51.2 MB);
  // CSR build completes before gather1 first writes hbuf
  int* H = (int*)hbuf;

  hipMemsetAsync(d_ws, 0, zero_bytes, stream);
  dim3 hgrid(NCHUNK, NPART);
  k_hist<<<hgrid, 256, 0, stream>>>(src, dst, H);
  k_reduce<<<(NN + 255) / 256, 256, 0, stream>>>(H, ic, onrm, inrm);
  k_scan_a<<<NB_SCAN, 256, 0, stream>>>(ic, bsum);
  k_scan_b<<<1, 128, 0, stream>>>(bsum, off);
  k_scan_c<<<NB_SCAN, 256, 0, stream>>>(ic, bsum, off);
  k_start<<<(NN + 255) / 256, 256, 0, stream>>>(H, off);
  k_fill2<<<hgrid, 256, 0, stream>>>(src, dst, H, csr);

  // layer 1: t = fp16((h * onrm) @ W1); h1 = fp16(relu(inrm * gather(t) + b1))
  k_matmul<float><<<(NN + BM - 1) / BM, 256, 0, stream>>>(h, W1, onrm, tbuf);
  k_gather<<<(NN * 64) / 256, 256, 0, stream>>>(tbuf, csr, off, inrm, b1, hbuf);
  // layer 2
  k_matmul<__half><<<(NN + BM - 1) / BM, 256, 0, stream>>>(hbuf, W2, onrm, tbuf);
  k_gather<<<(NN * 64) / 256, 256, 0, stream>>>(tbuf, csr, off, inrm, b2, hbuf);

  k_pool_partial<<<(NN + POOL_CHUNK - 1) / POOL_CHUNK, 128, 0, stream>>>(hbuf, n2g, sums);
  k_mlp<<<NG, 128, 0, stream>>>(sums, n2g, Wc1, bc1, Wc2, bc2, Wc3, bc3, out);
}